// Round 8
// baseline (102.662 us; speedup 1.0000x reference)
//
#include <hip/hip_runtime.h>

typedef __attribute__((ext_vector_type(8))) __bf16 bf16x8;
typedef __attribute__((ext_vector_type(4))) float f32x4;

#define NB 8
#define NN 2048
#define NF 256
#define NU 256

static __device__ __forceinline__ unsigned short f2bf(float f) {
    union { float f; unsigned u; } a; a.f = f;
    unsigned r = a.u + 0x7FFFu + ((a.u >> 16) & 1u);   // RNE, no NaN inputs
    return (unsigned short)(r >> 16);
}

// hardware async global->LDS, 16B/lane; compiler cannot sink/reorder this
static __device__ __forceinline__ void glds16(const void* g, void* l) {
    __builtin_amdgcn_global_load_lds(
        (const __attribute__((address_space(1))) void*)g,
        (__attribute__((address_space(3))) void*)l, 16, 0, 0);
}

// ---------------- kernel 0: W -> MFMA B-fragment layout (bf16) ---------------
// WTf[z][kc][ub][lane][e] = W_z[kc*32 + (lane>>4)*8 + e][ub*16 + (lane&15)]
__global__ __launch_bounds__(256) void wfrag_kernel(
    const float* __restrict__ Wm, const float* __restrict__ Wu,
    unsigned short* __restrict__ WTf) {
    int idx = blockIdx.x * 256 + threadIdx.x;   // 16384 total
    int l  = idx & 63;
    int ub = (idx >> 6) & 15;
    int kc = (idx >> 10) & 7;
    int z  = idx >> 13;
    const float* W = z ? Wu : Wm;
    int u  = ub * 16 + (l & 15);
    int k0 = kc * 32 + (l >> 4) * 8;
    unsigned short p[8];
#pragma unroll
    for (int e = 0; e < 8; ++e) p[e] = f2bf(W[(k0 + e) * NU + u]);
    uint4 v;
    v.x = (unsigned)p[0] | ((unsigned)p[1] << 16);
    v.y = (unsigned)p[2] | ((unsigned)p[3] << 16);
    v.z = (unsigned)p[4] | ((unsigned)p[5] << 16);
    v.w = (unsigned)p[6] | ((unsigned)p[7] << 16);
    *(uint4*)(WTf + (size_t)idx * 8) = v;
}

// ---------------- kernel 1: h = bf16(x @ W_msg), stored in B-frag order ------
// Hf[b][ib][ub][lane][e] = h[b][ib*32 + (lane>>4)*8 + e][ub*16 + (lane&15)]
__global__ __launch_bounds__(256) void h_kernel(
    const float* __restrict__ x, const unsigned short* __restrict__ WTf,
    unsigned short* __restrict__ Hf) {
    int t = threadIdx.x;
    int w = t >> 6, l = t & 63;
    int l15 = l & 15, lh = l >> 4;
    int m0 = blockIdx.x * 64 + w * 16;
    const f32x4 fz = {0.f, 0.f, 0.f, 0.f};
    f32x4 acc[16];
#pragma unroll
    for (int i = 0; i < 16; ++i) acc[i] = fz;
    const float* xrow = x + (size_t)(m0 + l15) * NF;
#pragma unroll
    for (int kc = 0; kc < 8; ++kc) {
        int k0 = kc * 32 + lh * 8;
        float4 xa = *(const float4*)(xrow + k0);
        float4 xb = *(const float4*)(xrow + k0 + 4);
        union { unsigned short s[8]; bf16x8 v; } af;
        af.s[0] = f2bf(xa.x); af.s[1] = f2bf(xa.y);
        af.s[2] = f2bf(xa.z); af.s[3] = f2bf(xa.w);
        af.s[4] = f2bf(xb.x); af.s[5] = f2bf(xb.y);
        af.s[6] = f2bf(xb.z); af.s[7] = f2bf(xb.w);
#pragma unroll
        for (int ub = 0; ub < 16; ++ub) {
            union { uint4 q; bf16x8 v; } bf;
            bf.q = *(const uint4*)(WTf + (size_t)(kc * 1024 + ub * 64 + l) * 8);
            acc[ub] = __builtin_amdgcn_mfma_f32_16x16x32_bf16(af.v, bf.v, acc[ub], 0, 0, 0);
        }
    }
    int bb = m0 >> 11;            // batch
    int n0 = m0 & (NN - 1);
    int ib = n0 >> 5;
    int kl = ((n0 & 31) >> 3) + (lh >> 1);
    int e0 = (lh & 1) * 4;
#pragma unroll
    for (int ub = 0; ub < 16; ++ub) {
        unsigned short p[4];
#pragma unroll
        for (int r = 0; r < 4; ++r) p[r] = f2bf(acc[ub][r]);
        size_t off = ((size_t)((bb * 64 + ib) * 16 + ub)) * 512 + (size_t)(kl * 16 + l15) * 8 + e0;
        uint2 v;
        v.x = (unsigned)p[0] | ((unsigned)p[1] << 16);
        v.y = (unsigned)p[2] | ((unsigned)p[3] << 16);
        *(uint2*)(Hf + off) = v;
    }
}

// ---------------- kernel R: adj int32 -> At[b][j][i] bf16 (+ rdeg) ----------
// 512 blocks (b = blk&7, j-stripe 32) x 256 thr. Per 64-row tile: coalesced
// int4 loads -> LDS-pad transpose -> coalesced bf16 writes. Exact per-j degree
// accumulated from the transposed dwords (bit test), no atomics.
__global__ __launch_bounds__(256) void repack_kernel(
    const int* __restrict__ adj, unsigned short* __restrict__ At,
    float* __restrict__ rdeg) {
    __shared__ unsigned short T[2][32][66];   // [buf][j][i] pad 66: ~2-way banks

    int blk = blockIdx.x;
    int b = blk & 7, jt = blk >> 3;
    int j0 = jt * 32;
    int t = threadIdx.x;
    int j4 = t & 7,  irow = t >> 3;   // load map: cols j4*4.., rows irow, irow+32
    int jr = t >> 3, i8 = t & 7;      // out map: row j0+jr, i-block i8*8

    const int* adjb = adj + (size_t)b * NN * NN + j0 + j4 * 4;
    unsigned short* Atb = At + (size_t)b * NN * NN;  // NN*NN ushorts per batch

    int dsum = 0;
    int4 rA0, rA1, rB0, rB1;

#define RLOAD(R0, R1, it) do {                                              \
    R0 = *(const int4*)(adjb + (size_t)((it) * 64 + irow) * NN);            \
    R1 = *(const int4*)(adjb + (size_t)((it) * 64 + irow + 32) * NN); } while (0)

#define RWRITE(BUF, R0, R1) do {                                            \
    T[BUF][j4 * 4 + 0][irow]      = (unsigned short)(R0.x * 0x3F80);        \
    T[BUF][j4 * 4 + 1][irow]      = (unsigned short)(R0.y * 0x3F80);        \
    T[BUF][j4 * 4 + 2][irow]      = (unsigned short)(R0.z * 0x3F80);        \
    T[BUF][j4 * 4 + 3][irow]      = (unsigned short)(R0.w * 0x3F80);        \
    T[BUF][j4 * 4 + 0][irow + 32] = (unsigned short)(R1.x * 0x3F80);        \
    T[BUF][j4 * 4 + 1][irow + 32] = (unsigned short)(R1.y * 0x3F80);        \
    T[BUF][j4 * 4 + 2][irow + 32] = (unsigned short)(R1.z * 0x3F80);        \
    T[BUF][j4 * 4 + 3][irow + 32] = (unsigned short)(R1.w * 0x3F80); } while (0)

#define ROUT(BUF, it) do {                                                  \
    unsigned d0 = *(const unsigned*)&T[BUF][jr][i8 * 8 + 0];                \
    unsigned d1 = *(const unsigned*)&T[BUF][jr][i8 * 8 + 2];                \
    unsigned d2 = *(const unsigned*)&T[BUF][jr][i8 * 8 + 4];                \
    unsigned d3 = *(const unsigned*)&T[BUF][jr][i8 * 8 + 6];                \
    dsum += (int)(((d0 >> 7) & 1) + ((d0 >> 23) & 1) + ((d1 >> 7) & 1) +    \
                  ((d1 >> 23) & 1) + ((d2 >> 7) & 1) + ((d2 >> 23) & 1) +   \
                  ((d3 >> 7) & 1) + ((d3 >> 23) & 1));                      \
    uint4 o; o.x = d0; o.y = d1; o.z = d2; o.w = d3;                        \
    *(uint4*)(Atb + (size_t)(j0 + jr) * NN + (it) * 64 + i8 * 8) = o; } while (0)

    RLOAD(rA0, rA1, 0);
    RLOAD(rB0, rB1, 1);
#pragma unroll 1
    for (int it = 0; it < 32; it += 2) {
        RWRITE(0, rA0, rA1);
        __syncthreads();
        if (it + 2 < 32) RLOAD(rA0, rA1, it + 2);
        ROUT(0, it);
        RWRITE(1, rB0, rB1);
        __syncthreads();
        if (it + 3 < 32) RLOAD(rB0, rB1, it + 3);
        ROUT(1, it + 1);
    }

    // deg: 8 threads (i8 groups) share row jr -> lane-bit 0..2 xor reduce
    dsum += __shfl_xor(dsum, 1, 64);
    dsum += __shfl_xor(dsum, 2, 64);
    dsum += __shfl_xor(dsum, 4, 64);
    if (i8 == 0)
        rdeg[(size_t)b * NN + j0 + jr] = dsum > 0 ? 1.0f / (float)dsum : 0.0f;
}

// ---------------- kernel 2: msg GEMM (m97 structure) + mean + upd + relu -----
// 512 blocks (b=blk&7, jt 64-j tile, uh 128-u half) x 256 thr (4 waves:
// wj = w&1 j-half32, wu = w>>1 u-half64). Both operands staged fragment-order
// via global_load_lds (3 issues/wave/chunk), K=32 chunks, 1 syncthreads/chunk.
// 24KB LDS, low VGPR -> 4+ blocks/CU hide the barrier vmcnt drain.
__global__ __launch_bounds__(256) void msg_kernel(
    const unsigned short* __restrict__ At, const unsigned short* __restrict__ Hf,
    const float* __restrict__ rdeg, const float* __restrict__ x,
    const unsigned short* __restrict__ WTf, const float* __restrict__ bias,
    float* __restrict__ out) {
    __shared__ uint4 Abuf[2][256];   // 4 jf-slots x 64 lanes x 16B
    __shared__ uint4 Bbuf[2][512];   // 8 g-slots  x 64 lanes x 16B

    int blk = blockIdx.x;
    int b = blk & 7, jt = (blk >> 3) & 31, uh = blk >> 8;
    int j0 = jt * 64;
    int t = threadIdx.x, w = t >> 6, l = t & 63;
    int wj = w & 1, wu = w >> 1;
    int l15 = l & 15, lh = l >> 4;

    // 3 staging issues per wave: id = w*3+k; id<4 -> A slot id, else B slot id-4
    const unsigned short* gcur[3];
    size_t gstep[3];
    uint4* lb0[3];
    uint4* lb1[3];
#pragma unroll
    for (int k = 0; k < 3; ++k) {
        int id = w * 3 + k;
        if (id < 4) {
            gcur[k] = At + (size_t)b * NN * NN + (size_t)(j0 + id * 16 + l15) * NN + lh * 8;
            gstep[k] = 32;                       // ushorts per chunk
            lb0[k] = &Abuf[0][id * 64 + l];
            lb1[k] = &Abuf[1][id * 64 + l];
        } else {
            int g = id - 4;
            gcur[k] = Hf + ((size_t)(b * 64) * 16 + uh * 8 + g) * 512 + (size_t)l * 8;
            gstep[k] = 16 * 512;
            lb0[k] = &Bbuf[0][g * 64 + l];
            lb1[k] = &Bbuf[1][g * 64 + l];
        }
    }

    const f32x4 fz = {0.f, 0.f, 0.f, 0.f};
    f32x4 acc[2][4];                 // [f][k4]
#pragma unroll
    for (int a = 0; a < 2; ++a)
#pragma unroll
        for (int c = 0; c < 4; ++c) acc[a][c] = fz;

    // prologue: stage chunk 0 into buf 0
#pragma unroll
    for (int k = 0; k < 3; ++k) {
        glds16(gcur[k], lb0[k]);
        gcur[k] += gstep[k];
    }
    __syncthreads();   // vmcnt drain -> buf0 ready

#pragma unroll 1
    for (int c = 0; c < 64; ++c) {
        int buf = c & 1;
        if (c < 63) {
#pragma unroll
            for (int k = 0; k < 3; ++k) {
                glds16(gcur[k], buf ? lb0[k] : lb1[k]);
                gcur[k] += gstep[k];
            }
        }
        bf16x8 af[2];
#pragma unroll
        for (int f = 0; f < 2; ++f) {
            union { uint4 q; bf16x8 v; } u;
            u.q = Abuf[buf][(wj * 2 + f) * 64 + l];
            af[f] = u.v;
        }
#pragma unroll
        for (int k4 = 0; k4 < 4; ++k4) {
            union { uint4 q; bf16x8 v; } u;
            u.q = Bbuf[buf][(wu * 4 + k4) * 64 + l];
#pragma unroll
            for (int f = 0; f < 2; ++f)
                acc[f][k4] = __builtin_amdgcn_mfma_f32_16x16x32_bf16(
                    af[f], u.v, acc[f][k4], 0, 0, 0);
        }
        __syncthreads();   // drains vmcnt -> next buf staged; LDS reuse safe
    }

    // scale by 1/deg (TF segment-mean: deg==0 -> 0)
#pragma unroll
    for (int f = 0; f < 2; ++f)
#pragma unroll
        for (int rr = 0; rr < 4; ++rr) {
            float sc = rdeg[(size_t)b * NN + j0 + (wj * 2 + f) * 16 + lh * 4 + rr];
#pragma unroll
            for (int k4 = 0; k4 < 4; ++k4) acc[f][k4][rr] *= sc;
        }

    // fused upd GEMM: acc += bf16(x_rows) @ W_upd
    const float* xb = x + ((size_t)b * NN + j0) * NF;
#pragma unroll
    for (int kc = 0; kc < 8; ++kc) {
        int k0 = kc * 32 + lh * 8;
        bf16x8 xf[2];
#pragma unroll
        for (int f = 0; f < 2; ++f) {
            const float* xr = xb + (size_t)((wj * 2 + f) * 16 + l15) * NF + k0;
            float4 xa = *(const float4*)xr;
            float4 xc = *(const float4*)(xr + 4);
            union { unsigned short sh[8]; bf16x8 v; } a2;
            a2.sh[0] = f2bf(xa.x); a2.sh[1] = f2bf(xa.y);
            a2.sh[2] = f2bf(xa.z); a2.sh[3] = f2bf(xa.w);
            a2.sh[4] = f2bf(xc.x); a2.sh[5] = f2bf(xc.y);
            a2.sh[6] = f2bf(xc.z); a2.sh[7] = f2bf(xc.w);
            xf[f] = a2.v;
        }
#pragma unroll
        for (int k4 = 0; k4 < 4; ++k4) {
            int ubg = uh * 8 + wu * 4 + k4;
            union { uint4 q; bf16x8 v; } bf;
            bf.q = *(const uint4*)(WTf + (size_t)(8192 + kc * 1024 + ubg * 64 + l) * 8);
#pragma unroll
            for (int f = 0; f < 2; ++f)
                acc[f][k4] = __builtin_amdgcn_mfma_f32_16x16x32_bf16(
                    xf[f], bf.v, acc[f][k4], 0, 0, 0);
        }
    }

    // epilogue: + bias, relu, store
    float* ob = out + ((size_t)b * NN + j0) * NU;
#pragma unroll
    for (int f = 0; f < 2; ++f)
#pragma unroll
        for (int k4 = 0; k4 < 4; ++k4) {
            int u = uh * 128 + (wu * 4 + k4) * 16 + l15;
            float bv = bias[u];
#pragma unroll
            for (int rr = 0; rr < 4; ++rr) {
                float v = acc[f][k4][rr] + bv;
                ob[(size_t)((wj * 2 + f) * 16 + lh * 4 + rr) * NU + u] = fmaxf(v, 0.f);
            }
        }
}

extern "C" void kernel_launch(void* const* d_in, const int* in_sizes, int n_in,
                              void* d_out, int out_size, void* d_ws, size_t ws_size,
                              hipStream_t stream) {
    const float* x    = (const float*)d_in[0];
    const int*   adj  = (const int*)d_in[1];
    const float* Wm   = (const float*)d_in[2];
    const float* Wu   = (const float*)d_in[3];
    const float* bias = (const float*)d_in[4];
    float* out = (float*)d_out;

    char* ws = (char*)d_ws;
    unsigned short* WTf  = (unsigned short*)(ws);                    // 256 KiB
    unsigned short* Hf   = (unsigned short*)(ws + (1ull << 20));     // 8 MiB @ 1M
    float*          rdeg = (float*)(ws + (12ull << 20));             // 64 KiB @ 12M
    unsigned short* At   = (unsigned short*)(ws + (16ull << 20));    // 64 MiB @ 16M

    wfrag_kernel<<<64, 256, 0, stream>>>(Wm, Wu, WTf);
    h_kernel<<<256, 256, 0, stream>>>(x, WTf, Hf);
    repack_kernel<<<512, 256, 0, stream>>>(adj, At, rdeg);
    msg_kernel<<<512, 256, 0, stream>>>(At, Hf, rdeg, x, WTf, bias, out);
}

// Round 9
// 85.329 us; speedup vs baseline: 1.2031x; 1.2031x over previous
//
#include <hip/hip_runtime.h>

typedef __attribute__((ext_vector_type(8))) __bf16 bf16x8;
typedef __attribute__((ext_vector_type(4))) float f32x4;

#define NB 8
#define NN 2048
#define NF 256
#define NU 256

static __device__ __forceinline__ unsigned short f2bf(float f) {
    union { float f; unsigned u; } a; a.f = f;
    unsigned r = a.u + 0x7FFFu + ((a.u >> 16) & 1u);   // RNE, no NaN inputs
    return (unsigned short)(r >> 16);
}

// hardware async global->LDS, 16B/lane; compiler cannot sink/reorder this
static __device__ __forceinline__ void glds16(const void* g, void* l) {
    __builtin_amdgcn_global_load_lds(
        (const __attribute__((address_space(1))) void*)g,
        (__attribute__((address_space(3))) void*)l, 16, 0, 0);
}

// ---------------- kernel 0: W -> MFMA B-fragment layout (bf16) ---------------
// WTf[z][kc][ub][lane][e] = W_z[kc*32 + (lane>>4)*8 + e][ub*16 + (lane&15)]
__global__ __launch_bounds__(256) void wfrag_kernel(
    const float* __restrict__ Wm, const float* __restrict__ Wu,
    unsigned short* __restrict__ WTf) {
    int idx = blockIdx.x * 256 + threadIdx.x;   // 16384 total
    int l  = idx & 63;
    int ub = (idx >> 6) & 15;
    int kc = (idx >> 10) & 7;
    int z  = idx >> 13;
    const float* W = z ? Wu : Wm;
    int u  = ub * 16 + (l & 15);
    int k0 = kc * 32 + (l >> 4) * 8;
    unsigned short p[8];
#pragma unroll
    for (int e = 0; e < 8; ++e) p[e] = f2bf(W[(k0 + e) * NU + u]);
    uint4 v;
    v.x = (unsigned)p[0] | ((unsigned)p[1] << 16);
    v.y = (unsigned)p[2] | ((unsigned)p[3] << 16);
    v.z = (unsigned)p[4] | ((unsigned)p[5] << 16);
    v.w = (unsigned)p[6] | ((unsigned)p[7] << 16);
    *(uint4*)(WTf + (size_t)idx * 8) = v;
}

// ---------------- kernel 1: h = bf16(x @ W_msg), stored in B-frag order ------
// Hf[b][ib][ub][lane][e] = h[b][ib*32 + (lane>>4)*8 + e][ub*16 + (lane&15)]
__global__ __launch_bounds__(256) void h_kernel(
    const float* __restrict__ x, const unsigned short* __restrict__ WTf,
    unsigned short* __restrict__ Hf) {
    int t = threadIdx.x;
    int w = t >> 6, l = t & 63;
    int l15 = l & 15, lh = l >> 4;
    int m0 = blockIdx.x * 64 + w * 16;
    const f32x4 fz = {0.f, 0.f, 0.f, 0.f};
    f32x4 acc[16];
#pragma unroll
    for (int i = 0; i < 16; ++i) acc[i] = fz;
    const float* xrow = x + (size_t)(m0 + l15) * NF;
#pragma unroll
    for (int kc = 0; kc < 8; ++kc) {
        int k0 = kc * 32 + lh * 8;
        float4 xa = *(const float4*)(xrow + k0);
        float4 xb = *(const float4*)(xrow + k0 + 4);
        union { unsigned short s[8]; bf16x8 v; } af;
        af.s[0] = f2bf(xa.x); af.s[1] = f2bf(xa.y);
        af.s[2] = f2bf(xa.z); af.s[3] = f2bf(xa.w);
        af.s[4] = f2bf(xb.x); af.s[5] = f2bf(xb.y);
        af.s[6] = f2bf(xb.z); af.s[7] = f2bf(xb.w);
#pragma unroll
        for (int ub = 0; ub < 16; ++ub) {
            union { uint4 q; bf16x8 v; } bf;
            bf.q = *(const uint4*)(WTf + (size_t)(kc * 1024 + ub * 64 + l) * 8);
            acc[ub] = __builtin_amdgcn_mfma_f32_16x16x32_bf16(af.v, bf.v, acc[ub], 0, 0, 0);
        }
    }
    int bb = m0 >> 11;            // batch
    int n0 = m0 & (NN - 1);
    int ib = n0 >> 5;
    int kl = ((n0 & 31) >> 3) + (lh >> 1);
    int e0 = (lh & 1) * 4;
#pragma unroll
    for (int ub = 0; ub < 16; ++ub) {
        unsigned short p[4];
#pragma unroll
        for (int r = 0; r < 4; ++r) p[r] = f2bf(acc[ub][r]);
        size_t off = ((size_t)((bb * 64 + ib) * 16 + ub)) * 512 + (size_t)(kl * 16 + l15) * 8 + e0;
        uint2 v;
        v.x = (unsigned)p[0] | ((unsigned)p[1] << 16);
        v.y = (unsigned)p[2] | ((unsigned)p[3] << 16);
        *(uint2*)(Hf + off) = v;
    }
}

// ---------------- kernel 2: ONE-PASS msg GEMM + mean + upd GEMM + relu -------
// 512 blocks (b=blk&7 XCD-pinned, jt j-tile 64, uh u-half 128) x 512 thr
// (8 waves: wj=w&1 j-half32, wu=w>>1). K-chunk = 32 i-rows, 64 chunks.
// Stage 1: glds adj int32 tile (coalesced rows) + glds Hf frags (HW queue,
// compiler-proof). Stage 2: in-LDS transpose int->bf16 A-frags (4x ds_read_b32
// + pack + 1 swizzled ds_write_b64/thread) with degree as by-product.
// m97 loop: issue-next -> transpose -> syncthreads -> MFMA -> issue-Hf.
__global__ __launch_bounds__(512) void msg_kernel(
    const int* __restrict__ adj, const unsigned short* __restrict__ Hf,
    const float* __restrict__ x, const unsigned short* __restrict__ WTf,
    const float* __restrict__ bias, float* __restrict__ out) {
    __shared__ int Ibuf[2][32 * 64];             // 2 x 8KB raw adj ints [i][j]
    __shared__ unsigned short Afr[2][64 * 32];   // 2 x 4KB bf16 A-frags, swizzled
    __shared__ unsigned short Hbuf[2][8 * 512];  // 2 x 8KB Hf B-frags (8 ub slots)
    __shared__ int degs[512];
    __shared__ float rdeg[64];

    int blk = blockIdx.x;
    int b = blk & 7, jt = (blk >> 3) & 31, uh = blk >> 8;
    int j0 = jt * 64;
    int t = threadIdx.x;
    int w = t >> 6, l = t & 63;
    int wj = w & 1, wu = w >> 1;
    int l15 = l & 15, lh = l >> 4;

    const f32x4 fz = {0.f, 0.f, 0.f, 0.f};
    f32x4 acc[2][2];                 // [jf][ub]
#pragma unroll
    for (int a = 0; a < 2; ++a)
#pragma unroll
        for (int c = 0; c < 2; ++c) acc[a][c] = fz;

    // glds sources (per-lane global addresses)
    // adj: wave w stages rows w*4 + (l>>4), 4 ints at col j0 + (l&15)*4
    const int* asrc = adj + (size_t)b * NN * NN + (size_t)(w * 4 + (l >> 4)) * NN
                      + j0 + (l & 15) * 4;
    // Hf: wave w stages ub-slot (uh*8 + w); lane l takes bytes l*16
    const unsigned short* hsrc = Hf + ((size_t)(b * 64) * 16 + uh * 8 + w) * 512
                                 + (size_t)l * 8;
    // LDS dests (base + lane*16)
    char* idst0 = (char*)(&Ibuf[0][0]) + w * 1024 + l * 16;
    char* idst1 = (char*)(&Ibuf[1][0]) + w * 1024 + l * 16;
    char* hdst0 = (char*)(&Hbuf[0][0]) + w * 1024 + l * 16;
    char* hdst1 = (char*)(&Hbuf[1][0]) + w * 1024 + l * 16;

    int dsum = 0;

    // prologue: stage chunk 0
    glds16(asrc, idst0);
    glds16(hsrc, hdst0);
    __syncthreads();   // vmcnt drain: chunk 0 staged

#pragma unroll 1
    for (int c = 0; c < 64; ++c) {
        int buf = c & 1;
        // A: issue adj ints for chunk c+1 into the other buffer
        if (c < 63)
            glds16(asrc + (size_t)(c + 1) * 32 * NN, buf ? idst0 : idst1);

        // B: transpose chunk c ints -> bf16 A-frags (this thread: col j=l, rows w*4..+3)
        {
            const int* ird = &Ibuf[buf][0];
            int r0 = ird[(w * 4 + 0) * 64 + l];
            int r1 = ird[(w * 4 + 1) * 64 + l];
            int r2 = ird[(w * 4 + 2) * 64 + l];
            int r3 = ird[(w * 4 + 3) * 64 + l];
            dsum += r0 + r1 + r2 + r3;
            uint2 pk;
            pk.x = ((unsigned)(r0 | (r1 << 16))) * 0x3F80u;
            pk.y = ((unsigned)(r2 | (r3 << 16))) * 0x3F80u;
            // byte(j,i) = j*64 + ((i*2) ^ ((j&3)<<4)); i0 = w*4 -> i*2 = w*8
            *(uint2*)((char*)(&Afr[buf][0]) + l * 64 + ((w * 8) ^ ((l & 3) << 4))) = pk;
        }

        __syncthreads();   // drains vmcnt (chunk c+1 ints, chunk c+... Hf) + lgkm (A-frags)

        // D: MFMA chunk c
        {
            bf16x8 af[2];
#pragma unroll
            for (int jf = 0; jf < 2; ++jf) {
                int j = wj * 32 + jf * 16 + l15;
                af[jf] = *(const bf16x8*)((const char*)(&Afr[buf][0]) +
                                          j * 64 + ((lh * 16) ^ ((j & 3) << 4)));
            }
#pragma unroll
            for (int ub = 0; ub < 2; ++ub) {
                union { uint4 q; bf16x8 v; } bq;
                bq.q = *(const uint4*)((const char*)(&Hbuf[buf][0]) +
                                       (wu * 2 + ub) * 1024 + l * 16);
#pragma unroll
                for (int jf = 0; jf < 2; ++jf)
                    acc[jf][ub] = __builtin_amdgcn_mfma_f32_16x16x32_bf16(
                        af[jf], bq.v, acc[jf][ub], 0, 0, 0);
            }
        }

        // E: issue Hf for chunk c+1 (after MFMA read of Hbuf[buf] -> WAR-safe)
        if (c < 63)
            glds16(hsrc + (size_t)(c + 1) * 16 * 512, buf ? hdst0 : hdst1);
    }

    // degree reduce: deg[j=l] = sum over 8 wave-groups
    degs[t] = dsum;
    __syncthreads();
    if (t < 64) {
        int d = 0;
#pragma unroll
        for (int g = 0; g < 8; ++g) d += degs[g * 64 + t];
        rdeg[t] = d > 0 ? 1.0f / (float)d : 0.0f;
    }
    __syncthreads();

    // scale msg accumulator by 1/deg (TF segment-mean: deg==0 -> 0)
#pragma unroll
    for (int jf = 0; jf < 2; ++jf)
#pragma unroll
        for (int rr = 0; rr < 4; ++rr) {
            float sc = rdeg[wj * 32 + jf * 16 + lh * 4 + rr];
#pragma unroll
            for (int ub = 0; ub < 2; ++ub) acc[jf][ub][rr] *= sc;
        }

    // fused upd GEMM: acc += bf16(x_rows) @ W_upd
    const float* xb = x + ((size_t)b * NN + j0) * NF;
#pragma unroll
    for (int kc = 0; kc < 8; ++kc) {
        int k0 = kc * 32 + lh * 8;
        bf16x8 xf[2];
#pragma unroll
        for (int jf = 0; jf < 2; ++jf) {
            const float* xr = xb + (size_t)(wj * 32 + jf * 16 + l15) * NF + k0;
            float4 xa = *(const float4*)xr;
            float4 xc = *(const float4*)(xr + 4);
            union { unsigned short sh[8]; bf16x8 v; } a2;
            a2.sh[0] = f2bf(xa.x); a2.sh[1] = f2bf(xa.y);
            a2.sh[2] = f2bf(xa.z); a2.sh[3] = f2bf(xa.w);
            a2.sh[4] = f2bf(xc.x); a2.sh[5] = f2bf(xc.y);
            a2.sh[6] = f2bf(xc.z); a2.sh[7] = f2bf(xc.w);
            xf[jf] = a2.v;
        }
#pragma unroll
        for (int ub = 0; ub < 2; ++ub) {
            int ubg = uh * 8 + wu * 2 + ub;
            union { uint4 q; bf16x8 v; } bf;
            bf.q = *(const uint4*)(WTf + (size_t)(8192 + kc * 1024 + ubg * 64 + l) * 8);
#pragma unroll
            for (int jf = 0; jf < 2; ++jf)
                acc[jf][ub] = __builtin_amdgcn_mfma_f32_16x16x32_bf16(
                    xf[jf], bf.v, acc[jf][ub], 0, 0, 0);
        }
    }

    // epilogue: + bias, relu, store
    float* ob = out + ((size_t)b * NN + j0) * NU;
#pragma unroll
    for (int jf = 0; jf < 2; ++jf)
#pragma unroll
        for (int ub = 0; ub < 2; ++ub) {
            int u = uh * 128 + (wu * 2 + ub) * 16 + l15;
            float bv = bias[u];
#pragma unroll
            for (int rr = 0; rr < 4; ++rr) {
                float v = acc[jf][ub][rr] + bv;
                ob[(size_t)(wj * 32 + jf * 16 + lh * 4 + rr) * NU + u] = fmaxf(v, 0.f);
            }
        }
}

extern "C" void kernel_launch(void* const* d_in, const int* in_sizes, int n_in,
                              void* d_out, int out_size, void* d_ws, size_t ws_size,
                              hipStream_t stream) {
    const float* x    = (const float*)d_in[0];
    const int*   adj  = (const int*)d_in[1];
    const float* Wm   = (const float*)d_in[2];
    const float* Wu   = (const float*)d_in[3];
    const float* bias = (const float*)d_in[4];
    float* out = (float*)d_out;

    char* ws = (char*)d_ws;
    unsigned short* WTf = (unsigned short*)(ws);                 // 256 KiB
    unsigned short* Hf  = (unsigned short*)(ws + (1ull << 20));  // 8 MiB @ 1M

    wfrag_kernel<<<64, 256, 0, stream>>>(Wm, Wu, WTf);
    h_kernel<<<256, 256, 0, stream>>>(x, WTf, Hf);
    msg_kernel<<<512, 512, 0, stream>>>(adj, Hf, x, WTf, bias, out);
}

// Round 10
// 85.100 us; speedup vs baseline: 1.2064x; 1.0027x over previous
//
#include <hip/hip_runtime.h>

typedef __attribute__((ext_vector_type(8))) __bf16 bf16x8;
typedef __attribute__((ext_vector_type(4))) float f32x4;

#define NB 8
#define NN 2048
#define NF 256
#define NU 256

static __device__ __forceinline__ unsigned short f2bf(float f) {
    union { float f; unsigned u; } a; a.f = f;
    unsigned r = a.u + 0x7FFFu + ((a.u >> 16) & 1u);   // RNE, no NaN inputs
    return (unsigned short)(r >> 16);
}

// hardware async global->LDS, 16B/lane; compiler cannot sink/reorder this
static __device__ __forceinline__ void glds16(const void* g, void* l) {
    __builtin_amdgcn_global_load_lds(
        (const __attribute__((address_space(1))) void*)g,
        (__attribute__((address_space(3))) void*)l, 16, 0, 0);
}

// barrier WITHOUT vmcnt drain: LDS ops flushed (lgkmcnt), global loads in flight
static __device__ __forceinline__ void barrier_lgkm() {
    asm volatile("s_waitcnt lgkmcnt(0)" ::: "memory");
    __builtin_amdgcn_s_barrier();
    asm volatile("" ::: "memory");
}

// ---------------- kernel 0: W -> MFMA B-fragment layout (bf16) ---------------
// WTf[z][kc][ub][lane][e] = W_z[kc*32 + (lane>>4)*8 + e][ub*16 + (lane&15)]
__global__ __launch_bounds__(256) void wfrag_kernel(
    const float* __restrict__ Wm, const float* __restrict__ Wu,
    unsigned short* __restrict__ WTf) {
    int idx = blockIdx.x * 256 + threadIdx.x;   // 16384 total
    int l  = idx & 63;
    int ub = (idx >> 6) & 15;
    int kc = (idx >> 10) & 7;
    int z  = idx >> 13;
    const float* W = z ? Wu : Wm;
    int u  = ub * 16 + (l & 15);
    int k0 = kc * 32 + (l >> 4) * 8;
    unsigned short p[8];
#pragma unroll
    for (int e = 0; e < 8; ++e) p[e] = f2bf(W[(k0 + e) * NU + u]);
    uint4 v;
    v.x = (unsigned)p[0] | ((unsigned)p[1] << 16);
    v.y = (unsigned)p[2] | ((unsigned)p[3] << 16);
    v.z = (unsigned)p[4] | ((unsigned)p[5] << 16);
    v.w = (unsigned)p[6] | ((unsigned)p[7] << 16);
    *(uint4*)(WTf + (size_t)idx * 8) = v;
}

// ---------------- kernel 1: h = bf16(x @ W_msg), stored in B-frag order ------
// Hf[b][ib][ub][lane][e] = h[b][ib*32 + (lane>>4)*8 + e][ub*16 + (lane&15)]
__global__ __launch_bounds__(256) void h_kernel(
    const float* __restrict__ x, const unsigned short* __restrict__ WTf,
    unsigned short* __restrict__ Hf) {
    int t = threadIdx.x;
    int w = t >> 6, l = t & 63;
    int l15 = l & 15, lh = l >> 4;
    int m0 = blockIdx.x * 64 + w * 16;
    const f32x4 fz = {0.f, 0.f, 0.f, 0.f};
    f32x4 acc[16];
#pragma unroll
    for (int i = 0; i < 16; ++i) acc[i] = fz;
    const float* xrow = x + (size_t)(m0 + l15) * NF;
#pragma unroll
    for (int kc = 0; kc < 8; ++kc) {
        int k0 = kc * 32 + lh * 8;
        float4 xa = *(const float4*)(xrow + k0);
        float4 xb = *(const float4*)(xrow + k0 + 4);
        union { unsigned short s[8]; bf16x8 v; } af;
        af.s[0] = f2bf(xa.x); af.s[1] = f2bf(xa.y);
        af.s[2] = f2bf(xa.z); af.s[3] = f2bf(xa.w);
        af.s[4] = f2bf(xb.x); af.s[5] = f2bf(xb.y);
        af.s[6] = f2bf(xb.z); af.s[7] = f2bf(xb.w);
#pragma unroll
        for (int ub = 0; ub < 16; ++ub) {
            union { uint4 q; bf16x8 v; } bf;
            bf.q = *(const uint4*)(WTf + (size_t)(kc * 1024 + ub * 64 + l) * 8);
            acc[ub] = __builtin_amdgcn_mfma_f32_16x16x32_bf16(af.v, bf.v, acc[ub], 0, 0, 0);
        }
    }
    int bb = m0 >> 11;            // batch
    int n0 = m0 & (NN - 1);
    int ib = n0 >> 5;
    int kl = ((n0 & 31) >> 3) + (lh >> 1);
    int e0 = (lh & 1) * 4;
#pragma unroll
    for (int ub = 0; ub < 16; ++ub) {
        unsigned short p[4];
#pragma unroll
        for (int r = 0; r < 4; ++r) p[r] = f2bf(acc[ub][r]);
        size_t off = ((size_t)((bb * 64 + ib) * 16 + ub)) * 512 + (size_t)(kl * 16 + l15) * 8 + e0;
        uint2 v;
        v.x = (unsigned)p[0] | ((unsigned)p[1] << 16);
        v.y = (unsigned)p[2] | ((unsigned)p[3] << 16);
        *(uint2*)(Hf + off) = v;
    }
}

// ---------------- kernel 2: ONE-PASS msg GEMM + mean + upd GEMM + relu -------
// Round 9 mapping, round 10 pipeline: quad-buffered glds staging, 3 chunks in
// flight, counted s_waitcnt vmcnt(4) (NEVER 0 in loop), raw s_barrier (no vm
// drain). Loop: wait(c done) -> barrier -> transpose c -> issue c+3 ->
// lgkm-barrier -> MFMA c.
__global__ __launch_bounds__(512) void msg_kernel(
    const int* __restrict__ adj, const unsigned short* __restrict__ Hf,
    const float* __restrict__ x, const unsigned short* __restrict__ WTf,
    const float* __restrict__ bias, float* __restrict__ out) {
    __shared__ int Ibuf[4][32 * 64];             // 4 x 8KB raw adj ints [i][j]
    __shared__ unsigned short Afr[2][64 * 32];   // 2 x 4KB bf16 A-frags, swizzled
    __shared__ unsigned short Hbuf[4][8 * 512];  // 4 x 8KB Hf B-frags (8 ub slots)
    __shared__ int degs[512];
    __shared__ float rdeg[64];

    int blk = blockIdx.x;
    int b = blk & 7, jt = (blk >> 3) & 31, uh = blk >> 8;
    int j0 = jt * 64;
    int t = threadIdx.x;
    int w = t >> 6, l = t & 63;
    int wj = w & 1, wu = w >> 1;
    int l15 = l & 15, lh = l >> 4;

    const f32x4 fz = {0.f, 0.f, 0.f, 0.f};
    f32x4 acc[2][2];                 // [jf][ub]
#pragma unroll
    for (int a = 0; a < 2; ++a)
#pragma unroll
        for (int c = 0; c < 2; ++c) acc[a][c] = fz;

    // glds sources (per-lane global addresses)
    const int* asrc = adj + (size_t)b * NN * NN + (size_t)(w * 4 + (l >> 4)) * NN
                      + j0 + (l & 15) * 4;
    const unsigned short* hsrc = Hf + ((size_t)(b * 64) * 16 + uh * 8 + w) * 512
                                 + (size_t)l * 8;
    char* Ibase = (char*)(&Ibuf[0][0]);
    char* Hbase = (char*)(&Hbuf[0][0]);
    int ldst = w * 1024 + l * 16;    // per-lane LDS offset within a buffer

    int dsum = 0;

    // prologue: chunks 0,1,2 in flight (6 glds/wave, issue order A,H per chunk)
#pragma unroll
    for (int p = 0; p < 3; ++p) {
        glds16(asrc + (size_t)p * 32 * NN, Ibase + p * 8192 + ldst);
        glds16(hsrc + (size_t)p * 16 * 512, Hbase + p * 8192 + ldst);
    }

#pragma unroll 1
    for (int c = 0; c < 64; ++c) {
        // chunk c's 2 loads done; chunks c+1,c+2 (4 ops) stay in flight
        asm volatile("s_waitcnt vmcnt(4)" ::: "memory");
        __builtin_amdgcn_sched_barrier(0);
        __builtin_amdgcn_s_barrier();    // all waves' chunk-c data visible

        // transpose chunk c ints -> bf16 A-frags (col j=l, rows w*4..w*4+3)
        {
            const int* ird = (const int*)(Ibase + (c & 3) * 8192);
            int r0 = ird[(w * 4 + 0) * 64 + l];
            int r1 = ird[(w * 4 + 1) * 64 + l];
            int r2 = ird[(w * 4 + 2) * 64 + l];
            int r3 = ird[(w * 4 + 3) * 64 + l];
            dsum += r0 + r1 + r2 + r3;
            uint2 pk;
            pk.x = ((unsigned)(r0 | (r1 << 16))) * 0x3F80u;
            pk.y = ((unsigned)(r2 | (r3 << 16))) * 0x3F80u;
            // byte(j,i) = j*64 + ((i*2) ^ ((j&3)<<4)); i0 = w*4 -> i*2 = w*8
            *(uint2*)((char*)(&Afr[c & 1][0]) + l * 64 + ((w * 8) ^ ((l & 3) << 4))) = pk;
        }

        // issue chunk c+3 into ring slot (c+3)&3 (clamped tail: lands only in
        // dead buffers -- audited; keeps vmcnt count exact at 6)
        {
            int cn = (c + 3 < 64) ? c + 3 : 63;
            glds16(asrc + (size_t)cn * 32 * NN, Ibase + ((c + 3) & 3) * 8192 + ldst);
            glds16(hsrc + (size_t)cn * 16 * 512, Hbase + ((c + 3) & 3) * 8192 + ldst);
        }

        barrier_lgkm();   // A-frag writes visible; glds stay in flight

        // MFMA chunk c
        {
            bf16x8 af[2];
#pragma unroll
            for (int jf = 0; jf < 2; ++jf) {
                int j = wj * 32 + jf * 16 + l15;
                af[jf] = *(const bf16x8*)((const char*)(&Afr[c & 1][0]) +
                                          j * 64 + ((lh * 16) ^ ((j & 3) << 4)));
            }
#pragma unroll
            for (int ub = 0; ub < 2; ++ub) {
                union { uint4 q; bf16x8 v; } bq;
                bq.q = *(const uint4*)((const char*)(Hbase + (c & 3) * 8192) +
                                       (wu * 2 + ub) * 1024 + l * 16);
#pragma unroll
                for (int jf = 0; jf < 2; ++jf)
                    acc[jf][ub] = __builtin_amdgcn_mfma_f32_16x16x32_bf16(
                        af[jf], bq.v, acc[jf][ub], 0, 0, 0);
            }
        }
    }

    asm volatile("s_waitcnt vmcnt(0)" ::: "memory");   // drain tail glds

    // degree reduce: deg[j=l] = sum over 8 wave-groups
    degs[t] = dsum;
    __syncthreads();
    if (t < 64) {
        int d = 0;
#pragma unroll
        for (int g = 0; g < 8; ++g) d += degs[g * 64 + t];
        rdeg[t] = d > 0 ? 1.0f / (float)d : 0.0f;
    }
    __syncthreads();

    // scale msg accumulator by 1/deg (TF segment-mean: deg==0 -> 0)
#pragma unroll
    for (int jf = 0; jf < 2; ++jf)
#pragma unroll
        for (int rr = 0; rr < 4; ++rr) {
            float sc = rdeg[wj * 32 + jf * 16 + lh * 4 + rr];
#pragma unroll
            for (int ub = 0; ub < 2; ++ub) acc[jf][ub][rr] *= sc;
        }

    // fused upd GEMM: acc += bf16(x_rows) @ W_upd
    const float* xb = x + ((size_t)b * NN + j0) * NF;
#pragma unroll
    for (int kc = 0; kc < 8; ++kc) {
        int k0 = kc * 32 + lh * 8;
        bf16x8 xf[2];
#pragma unroll
        for (int jf = 0; jf < 2; ++jf) {
            const float* xr = xb + (size_t)(wj * 32 + jf * 16 + l15) * NF + k0;
            float4 xa = *(const float4*)xr;
            float4 xc = *(const float4*)(xr + 4);
            union { unsigned short sh[8]; bf16x8 v; } a2;
            a2.sh[0] = f2bf(xa.x); a2.sh[1] = f2bf(xa.y);
            a2.sh[2] = f2bf(xa.z); a2.sh[3] = f2bf(xa.w);
            a2.sh[4] = f2bf(xc.x); a2.sh[5] = f2bf(xc.y);
            a2.sh[6] = f2bf(xc.z); a2.sh[7] = f2bf(xc.w);
            xf[jf] = a2.v;
        }
#pragma unroll
        for (int ub = 0; ub < 2; ++ub) {
            int ubg = uh * 8 + wu * 2 + ub;
            union { uint4 q; bf16x8 v; } bf;
            bf.q = *(const uint4*)(WTf + (size_t)(8192 + kc * 1024 + ubg * 64 + l) * 8);
#pragma unroll
            for (int jf = 0; jf < 2; ++jf)
                acc[jf][ub] = __builtin_amdgcn_mfma_f32_16x16x32_bf16(
                    xf[jf], bf.v, acc[jf][ub], 0, 0, 0);
        }
    }

    // epilogue: + bias, relu, store
    float* ob = out + ((size_t)b * NN + j0) * NU;
#pragma unroll
    for (int jf = 0; jf < 2; ++jf)
#pragma unroll
        for (int ub = 0; ub < 2; ++ub) {
            int u = uh * 128 + (wu * 2 + ub) * 16 + l15;
            float bv = bias[u];
#pragma unroll
            for (int rr = 0; rr < 4; ++rr) {
                float v = acc[jf][ub][rr] + bv;
                ob[(size_t)(wj * 32 + jf * 16 + lh * 4 + rr) * NU + u] = fmaxf(v, 0.f);
            }
        }
}

extern "C" void kernel_launch(void* const* d_in, const int* in_sizes, int n_in,
                              void* d_out, int out_size, void* d_ws, size_t ws_size,
                              hipStream_t stream) {
    const float* x    = (const float*)d_in[0];
    const int*   adj  = (const int*)d_in[1];
    const float* Wm   = (const float*)d_in[2];
    const float* Wu   = (const float*)d_in[3];
    const float* bias = (const float*)d_in[4];
    float* out = (float*)d_out;

    char* ws = (char*)d_ws;
    unsigned short* WTf = (unsigned short*)(ws);                 // 256 KiB
    unsigned short* Hf  = (unsigned short*)(ws + (1ull << 20));  // 8 MiB @ 1M

    wfrag_kernel<<<64, 256, 0, stream>>>(Wm, Wu, WTf);
    h_kernel<<<256, 256, 0, stream>>>(x, WTf, Hf);
    msg_kernel<<<512, 512, 0, stream>>>(adj, Hf, x, WTf, bias, out);
}

// Round 11
// 78.423 us; speedup vs baseline: 1.3091x; 1.0851x over previous
//
#include <hip/hip_runtime.h>

typedef __attribute__((ext_vector_type(8))) __bf16 bf16x8;
typedef __attribute__((ext_vector_type(4))) float f32x4;

#define NB 8
#define NN 2048
#define NF 256
#define NU 256

static __device__ __forceinline__ unsigned short f2bf(float f) {
    union { float f; unsigned u; } a; a.f = f;
    unsigned r = a.u + 0x7FFFu + ((a.u >> 16) & 1u);   // RNE, no NaN inputs
    return (unsigned short)(r >> 16);
}

// hardware async global->LDS, 16B/lane
static __device__ __forceinline__ void glds16(const void* g, void* l) {
    __builtin_amdgcn_global_load_lds(
        (const __attribute__((address_space(1))) void*)g,
        (__attribute__((address_space(3))) void*)l, 16, 0, 0);
}

// ---------------- kernel 0: W -> MFMA B-fragment layout (bf16) ---------------
__global__ __launch_bounds__(256) void wfrag_kernel(
    const float* __restrict__ Wm, const float* __restrict__ Wu,
    unsigned short* __restrict__ WTf) {
    int idx = blockIdx.x * 256 + threadIdx.x;   // 16384 total
    int l  = idx & 63;
    int ub = (idx >> 6) & 15;
    int kc = (idx >> 10) & 7;
    int z  = idx >> 13;
    const float* W = z ? Wu : Wm;
    int u  = ub * 16 + (l & 15);
    int k0 = kc * 32 + (l >> 4) * 8;
    unsigned short p[8];
#pragma unroll
    for (int e = 0; e < 8; ++e) p[e] = f2bf(W[(k0 + e) * NU + u]);
    uint4 v;
    v.x = (unsigned)p[0] | ((unsigned)p[1] << 16);
    v.y = (unsigned)p[2] | ((unsigned)p[3] << 16);
    v.z = (unsigned)p[4] | ((unsigned)p[5] << 16);
    v.w = (unsigned)p[6] | ((unsigned)p[7] << 16);
    *(uint4*)(WTf + (size_t)idx * 8) = v;
}

// ---------------- kernel 1: h = bf16(x @ W_msg), stored in B-frag order ------
// Hf[b][ib][ub][lane][e] = h[b][ib*32 + (lane>>4)*8 + e][ub*16 + (lane&15)]
__global__ __launch_bounds__(256) void h_kernel(
    const float* __restrict__ x, const unsigned short* __restrict__ WTf,
    unsigned short* __restrict__ Hf) {
    int t = threadIdx.x;
    int w = t >> 6, l = t & 63;
    int l15 = l & 15, lh = l >> 4;
    int m0 = blockIdx.x * 64 + w * 16;
    const f32x4 fz = {0.f, 0.f, 0.f, 0.f};
    f32x4 acc[16];
#pragma unroll
    for (int i = 0; i < 16; ++i) acc[i] = fz;
    const float* xrow = x + (size_t)(m0 + l15) * NF;
#pragma unroll
    for (int kc = 0; kc < 8; ++kc) {
        int k0 = kc * 32 + lh * 8;
        float4 xa = *(const float4*)(xrow + k0);
        float4 xb = *(const float4*)(xrow + k0 + 4);
        union { unsigned short s[8]; bf16x8 v; } af;
        af.s[0] = f2bf(xa.x); af.s[1] = f2bf(xa.y);
        af.s[2] = f2bf(xa.z); af.s[3] = f2bf(xa.w);
        af.s[4] = f2bf(xb.x); af.s[5] = f2bf(xb.y);
        af.s[6] = f2bf(xb.z); af.s[7] = f2bf(xb.w);
#pragma unroll
        for (int ub = 0; ub < 16; ++ub) {
            union { uint4 q; bf16x8 v; } bf;
            bf.q = *(const uint4*)(WTf + (size_t)(kc * 1024 + ub * 64 + l) * 8);
            acc[ub] = __builtin_amdgcn_mfma_f32_16x16x32_bf16(af.v, bf.v, acc[ub], 0, 0, 0);
        }
    }
    int bb = m0 >> 11;
    int n0 = m0 & (NN - 1);
    int ib = n0 >> 5;
    int kl = ((n0 & 31) >> 3) + (lh >> 1);
    int e0 = (lh & 1) * 4;
#pragma unroll
    for (int ub = 0; ub < 16; ++ub) {
        unsigned short p[4];
#pragma unroll
        for (int r = 0; r < 4; ++r) p[r] = f2bf(acc[ub][r]);
        size_t off = ((size_t)((bb * 64 + ib) * 16 + ub)) * 512 + (size_t)(kl * 16 + l15) * 8 + e0;
        uint2 v;
        v.x = (unsigned)p[0] | ((unsigned)p[1] << 16);
        v.y = (unsigned)p[2] | ((unsigned)p[3] << 16);
        *(uint2*)(Hf + off) = v;
    }
}

// ---------------- kernel 2: ONE-PASS msg GEMM + mean + upd GEMM + relu -------
// 512 blocks (b=blk&7 XCD-pinned, jt j-tile 32) x 512 thr (8 waves, each u32).
// adj read ONCE; Hf read once per block (L2-resident). Chunk K=64, 32 chunks.
// adj: glds ring-4 (3 ahead). Hf: inline-asm dwordx4 ("=&v") register dbuf,
// 1 chunk ahead. Counted waits: top vmcnt(10), pre-MFMA lgkm(0)+vmcnt(6).
#define SWZ(j) ((((j) ^ ((j) >> 3)) & 7) << 4)

__global__ __launch_bounds__(512, 4) void msg_kernel(
    const int* __restrict__ adj, const unsigned short* __restrict__ Hf,
    const float* __restrict__ x, const unsigned short* __restrict__ WTf,
    const float* __restrict__ bias, float* __restrict__ out) {
    __shared__ int Ibuf[4][64 * 32];            // 4 x 8KB raw adj ints [i 0..63][j 0..31]
    __shared__ unsigned short Afr[32 * 64];     // 4KB bf16 A-frags [j][i], swizzled
    __shared__ int degs[512];
    __shared__ float rdeg[32];

    int blk = blockIdx.x;
    int b = blk & 7, jt = blk >> 3;   // jt 0..63
    int j0 = jt * 32;
    int t = threadIdx.x;
    int w = t >> 6, l = t & 63;       // w = wave = u-tile 32 (ubg = w*2+ub)
    int l15 = l & 15, lh = l >> 4;
    int jj = t & 31, ig = t >> 5;     // transpose map: col jj, rows ig*4..+3 (ig 0..15)

    const f32x4 fz = {0.f, 0.f, 0.f, 0.f};
    f32x4 acc[2][2];                  // [jf][ub]
#pragma unroll
    for (int a = 0; a < 2; ++a)
#pragma unroll
        for (int c = 0; c < 2; ++c) acc[a][c] = fz;

    // adj glds: wave w stages rows w*8+(l>>3), cols j0+(l&7)*4 (linear lane*16 ✓)
    const int* asrc = adj + (size_t)b * NN * NN + (size_t)(w * 8 + (l >> 3)) * NN
                      + j0 + (l & 7) * 4;
    char* Idst = (char*)(&Ibuf[0][0]) + w * 1024;   // + slot*8192
    // Hf asm loads: per chunk c, bytes c*32768 + ic*16384 + ub*1024 from:
    const char* hsrc = (const char*)(Hf + ((size_t)(b * 64) * 16 + w * 2) * 512
                                     + (size_t)l * 8);

    uint4 hA[4], hB[4];               // Hf register dbuf: [ic*2+ub]
    int dsum = 0;

#define HLOAD(H, cc) do {                                                     \
    int _cb = ((cc) < 31) ? (cc) : 31;                                        \
    const char* _p0 = hsrc + (size_t)_cb * 32768;                             \
    const char* _p1 = _p0 + 16384;                                            \
    asm volatile("global_load_dwordx4 %0, %1, off"             : "=&v"(H[0]) : "v"(_p0)); \
    asm volatile("global_load_dwordx4 %0, %1, off offset:1024" : "=&v"(H[1]) : "v"(_p0)); \
    asm volatile("global_load_dwordx4 %0, %1, off"             : "=&v"(H[2]) : "v"(_p1)); \
    asm volatile("global_load_dwordx4 %0, %1, off offset:1024" : "=&v"(H[3]) : "v"(_p1)); \
} while (0)

#define AISSUE(c3) do {                                                       \
    int _cn = ((c3) < 31) ? (c3) : 31;                                        \
    glds16(asrc + (size_t)_cn * 64 * NN, Idst + ((c3) & 3) * 8192);           \
} while (0)

#define TRANSPOSE(cc) do {                                                    \
    const int* _ird = (const int*)((const char*)(&Ibuf[0][0]) + ((cc) & 3) * 8192); \
    int _r0 = _ird[(ig * 4 + 0) * 32 + jj];                                   \
    int _r1 = _ird[(ig * 4 + 1) * 32 + jj];                                   \
    int _r2 = _ird[(ig * 4 + 2) * 32 + jj];                                   \
    int _r3 = _ird[(ig * 4 + 3) * 32 + jj];                                   \
    dsum += _r0 + _r1 + _r2 + _r3;                                            \
    uint2 _pk;                                                                \
    _pk.x = ((unsigned)(_r0 | (_r1 << 16))) * 0x3F80u;                        \
    _pk.y = ((unsigned)(_r2 | (_r3 << 16))) * 0x3F80u;                        \
    *(uint2*)((char*)Afr + jj * 128 + ((ig * 8) ^ SWZ(jj))) = _pk;            \
} while (0)

#define MFMA_PH(H) do {                                                       \
    bf16x8 _af[2][2];                                                         \
    _Pragma("unroll")                                                         \
    for (int jf = 0; jf < 2; ++jf) {                                          \
        int _j = jf * 16 + l15;                                               \
        _Pragma("unroll")                                                     \
        for (int ic = 0; ic < 2; ++ic)                                        \
            _af[jf][ic] = *(const bf16x8*)((const char*)Afr + _j * 128 +      \
                                           ((ic * 64 + lh * 16) ^ SWZ(_j)));  \
    }                                                                         \
    _Pragma("unroll")                                                         \
    for (int ic = 0; ic < 2; ++ic)                                            \
        _Pragma("unroll")                                                     \
        for (int ub = 0; ub < 2; ++ub) {                                      \
            union { uint4 q; bf16x8 v; } _bq;                                 \
            _bq.q = H[ic * 2 + ub];                                           \
            _Pragma("unroll")                                                 \
            for (int jf = 0; jf < 2; ++jf)                                    \
                acc[jf][ub] = __builtin_amdgcn_mfma_f32_16x16x32_bf16(        \
                    _af[jf][ic], _bq.v, acc[jf][ub], 0, 0, 0);                \
        }                                                                     \
} while (0)

#define TOPW(n) do { asm volatile("s_waitcnt vmcnt(" #n ")" ::: "memory");    \
    __builtin_amdgcn_sched_barrier(0); __builtin_amdgcn_s_barrier(); } while (0)
#define MFMAW(n) do { asm volatile("s_waitcnt lgkmcnt(0) vmcnt(" #n ")" ::: "memory"); \
    __builtin_amdgcn_sched_barrier(0); __builtin_amdgcn_s_barrier(); } while (0)

    // prologue (vmem order: A0, H0x4, A1, A2)
    glds16(asrc, Idst);
    HLOAD(hA, 0);
    glds16(asrc + (size_t)64 * NN, Idst + 8192);
    glds16(asrc + (size_t)128 * NN, Idst + 16384);

    // c = 0  (top: need A0 -> 6 newer; mfma: need H0 -> 7 newer)
    TOPW(6);
    TRANSPOSE(0); HLOAD(hB, 1); AISSUE(3);
    MFMAW(7);
    MFMA_PH(hA);
    // c = 1  (top: need A1 -> 6 newer; mfma: need H1 -> 6 newer)
    TOPW(6);
    TRANSPOSE(1); HLOAD(hA, 2); AISSUE(4);
    MFMAW(6);
    MFMA_PH(hB);

    // steady: c = 2..31 (top: 10 newer than A(c); mfma: 6 newer than H(c))
#pragma unroll 1
    for (int cc = 2; cc < 32; cc += 2) {
        TOPW(10);
        TRANSPOSE(cc); HLOAD(hB, cc + 1); AISSUE(cc + 3);
        MFMAW(6);
        MFMA_PH(hA);

        TOPW(10);
        TRANSPOSE(cc + 1); HLOAD(hA, cc + 2); AISSUE(cc + 4);
        MFMAW(6);
        MFMA_PH(hB);
    }

    asm volatile("s_waitcnt vmcnt(0)" ::: "memory");   // drain tail

    // degree reduce: deg[j=jj] = sum over 16 ig groups
    degs[t] = dsum;
    __syncthreads();
    if (t < 32) {
        int d = 0;
#pragma unroll
        for (int g = 0; g < 16; ++g) d += degs[g * 32 + t];
        rdeg[t] = d > 0 ? 1.0f / (float)d : 0.0f;
    }
    __syncthreads();

    // scale msg accumulator by 1/deg (TF segment-mean: deg==0 -> 0)
#pragma unroll
    for (int jf = 0; jf < 2; ++jf)
#pragma unroll
        for (int rr = 0; rr < 4; ++rr) {
            float sc = rdeg[jf * 16 + lh * 4 + rr];
#pragma unroll
            for (int ub = 0; ub < 2; ++ub) acc[jf][ub][rr] *= sc;
        }

    // fused upd GEMM: acc += bf16(x_rows) @ W_upd
    const float* xb = x + ((size_t)b * NN + j0) * NF;
#pragma unroll
    for (int kc = 0; kc < 8; ++kc) {
        int k0 = kc * 32 + lh * 8;
        bf16x8 xf[2];
#pragma unroll
        for (int jf = 0; jf < 2; ++jf) {
            const float* xr = xb + (size_t)(jf * 16 + l15) * NF + k0;
            float4 xa = *(const float4*)xr;
            float4 xc = *(const float4*)(xr + 4);
            union { unsigned short sh[8]; bf16x8 v; } a2;
            a2.sh[0] = f2bf(xa.x); a2.sh[1] = f2bf(xa.y);
            a2.sh[2] = f2bf(xa.z); a2.sh[3] = f2bf(xa.w);
            a2.sh[4] = f2bf(xc.x); a2.sh[5] = f2bf(xc.y);
            a2.sh[6] = f2bf(xc.z); a2.sh[7] = f2bf(xc.w);
            xf[jf] = a2.v;
        }
#pragma unroll
        for (int ub = 0; ub < 2; ++ub) {
            int ubg = w * 2 + ub;
            union { uint4 q; bf16x8 v; } bf;
            bf.q = *(const uint4*)(WTf + (size_t)(8192 + kc * 1024 + ubg * 64 + l) * 8);
#pragma unroll
            for (int jf = 0; jf < 2; ++jf)
                acc[jf][ub] = __builtin_amdgcn_mfma_f32_16x16x32_bf16(
                    xf[jf], bf.v, acc[jf][ub], 0, 0, 0);
        }
    }

    // epilogue: + bias, relu, store
    float* ob = out + ((size_t)b * NN + j0) * NU;
#pragma unroll
    for (int jf = 0; jf < 2; ++jf)
#pragma unroll
        for (int ub = 0; ub < 2; ++ub) {
            int u = (w * 2 + ub) * 16 + l15;
            float bv = bias[u];
#pragma unroll
            for (int rr = 0; rr < 4; ++rr) {
                float v = acc[jf][ub][rr] + bv;
                ob[(size_t)(jf * 16 + lh * 4 + rr) * NU + u] = fmaxf(v, 0.f);
            }
        }
}

extern "C" void kernel_launch(void* const* d_in, const int* in_sizes, int n_in,
                              void* d_out, int out_size, void* d_ws, size_t ws_size,
                              hipStream_t stream) {
    const float* x    = (const float*)d_in[0];
    const int*   adj  = (const int*)d_in[1];
    const float* Wm   = (const float*)d_in[2];
    const float* Wu   = (const float*)d_in[3];
    const float* bias = (const float*)d_in[4];
    float* out = (float*)d_out;

    char* ws = (char*)d_ws;
    unsigned short* WTf = (unsigned short*)(ws);                 // 256 KiB
    unsigned short* Hf  = (unsigned short*)(ws + (1ull << 20));  // 8 MiB @ 1M

    wfrag_kernel<<<64, 256, 0, stream>>>(Wm, Wu, WTf);
    h_kernel<<<256, 256, 0, stream>>>(x, WTf, Hf);
    msg_kernel<<<512, 512, 0, stream>>>(adj, Hf, x, WTf, bias, out);
}